// Round 1
// baseline (606.528 us; speedup 1.0000x reference)
//
#include <hip/hip_runtime.h>
#include <hip/hip_bf16.h>
#include <stdint.h>

typedef float v4f __attribute__((ext_vector_type(4)));
typedef short v8s __attribute__((ext_vector_type(8)));

#define GEMM_M 8192
#define GEMM_N 4096
#define GEMM_K 4096
#define BM 128
#define BN 128
#define BK 32

// ---------------- prep kernels ----------------

__global__ void copy_w_kernel(const float4* __restrict__ src, float4* __restrict__ dst, int n4) {
    int i = blockIdx.x * blockDim.x + threadIdx.x;
    if (i < n4) dst[i] = src[i];
}

__global__ void scatter_add_kernel(float* __restrict__ w, const float* __restrict__ vals,
                                   const int* __restrict__ rows, const int* __restrict__ cols,
                                   int nnz) {
    int i = blockIdx.x * blockDim.x + threadIdx.x;
    if (i < nnz) {
        atomicAdd(&w[(size_t)rows[i] * GEMM_K + cols[i]], vals[i] /* * SCALING=1.0 */);
    }
}

__device__ __forceinline__ uint16_t f2bf(float f) {
    union { float f; uint32_t u; } v; v.f = f;
    uint32_t r = v.u + 0x7FFFu + ((v.u >> 16) & 1u);   // round-to-nearest-even
    return (uint16_t)(r >> 16);
}

// fp32 -> bf16, 8 elements per thread
__global__ void cvt_bf16_kernel(const float* __restrict__ src, uint16_t* __restrict__ dst, size_t n8) {
    size_t i = (size_t)blockIdx.x * blockDim.x + threadIdx.x;
    if (i >= n8) return;
    const float4* s = (const float4*)src + i * 2;
    float4 a = s[0];
    float4 b = s[1];
    union { v8s v; uint16_t u[8]; } o;
    o.u[0] = f2bf(a.x); o.u[1] = f2bf(a.y); o.u[2] = f2bf(a.z); o.u[3] = f2bf(a.w);
    o.u[4] = f2bf(b.x); o.u[5] = f2bf(b.y); o.u[6] = f2bf(b.z); o.u[7] = f2bf(b.w);
    *(v8s*)(dst + i * 8) = o.v;
}

// ---------------- GEMM (m97 structure) ----------------
// C[M,N] = A[M,K] (bf16, row-major) * B[N,K]^T (bf16, row-major) + bias[N]
// 256 threads = 4 waves; each wave computes a 64x64 sub-tile as 4x4 MFMAs of 16x16x32.

__device__ __forceinline__ void gload_lds16(const void* g, void* lds) {
    __builtin_amdgcn_global_load_lds(
        (const __attribute__((address_space(1))) void*)(uintptr_t)g,
        (__attribute__((address_space(3))) void*)(uintptr_t)lds,
        16, 0, 0);
}

__global__ __launch_bounds__(256) void gemm_bt_kernel(
    const uint16_t* __restrict__ A,   // [M,K] bf16 bits
    const uint16_t* __restrict__ B,   // [N,K] bf16 bits
    const float* __restrict__ bias,   // [N]
    float* __restrict__ C)            // [M,N] fp32
{
    __shared__ __attribute__((aligned(16))) uint16_t As[BM * BK];  // 8 KiB, unpadded (global_load_lds)
    __shared__ __attribute__((aligned(16))) uint16_t Bs[BN * BK];  // 8 KiB

    const int tid  = threadIdx.x;
    const int lane = tid & 63;
    const int wv   = tid >> 6;     // wave id 0..3
    const int wy   = wv >> 1;      // m half (0,1)
    const int wx   = wv & 1;       // n half (0,1)
    const int lrow = lane & 15;
    const int quad = lane >> 4;

    const int m0 = blockIdx.y * BM;
    const int n0 = blockIdx.x * BN;

    // staging: 512 x 16B transfers per tile; transfer idx = wv*2+j (wave-uniform),
    // elem8 = idx*64 + lane; LDS dst = base + elem8*16 (lane-contiguous, HW requirement)
    const int e0 = (wv * 2 + 0) * 64 + lane;
    const int e1 = (wv * 2 + 1) * 64 + lane;
    const uint16_t* a_g0 = A + (size_t)(m0 + (e0 >> 2)) * GEMM_K + (e0 & 3) * 8;
    const uint16_t* a_g1 = A + (size_t)(m0 + (e1 >> 2)) * GEMM_K + (e1 & 3) * 8;
    const uint16_t* b_g0 = B + (size_t)(n0 + (e0 >> 2)) * GEMM_K + (e0 & 3) * 8;
    const uint16_t* b_g1 = B + (size_t)(n0 + (e1 >> 2)) * GEMM_K + (e1 & 3) * 8;
    uint16_t* a_l0 = As + e0 * 8;
    uint16_t* a_l1 = As + e1 * 8;
    uint16_t* b_l0 = Bs + e0 * 8;
    uint16_t* b_l1 = Bs + e1 * 8;

    v4f acc[4][4];
#pragma unroll
    for (int i = 0; i < 4; i++)
#pragma unroll
        for (int j = 0; j < 4; j++) acc[i][j] = (v4f){0.f, 0.f, 0.f, 0.f};

    for (int k0 = 0; k0 < GEMM_K; k0 += BK) {
        gload_lds16(a_g0 + k0, a_l0);
        gload_lds16(a_g1 + k0, a_l1);
        gload_lds16(b_g0 + k0, b_l0);
        gload_lds16(b_g1 + k0, b_l1);
        __syncthreads();   // compiler emits vmcnt(0) drain before s_barrier -> tiles ready

        v8s af[4], bf[4];
#pragma unroll
        for (int t = 0; t < 4; t++)
            af[t] = *(const v8s*)(As + (wy * 64 + t * 16 + lrow) * BK + quad * 8);
#pragma unroll
        for (int t = 0; t < 4; t++)
            bf[t] = *(const v8s*)(Bs + (wx * 64 + t * 16 + lrow) * BK + quad * 8);

#pragma unroll
        for (int i = 0; i < 4; i++)
#pragma unroll
            for (int j = 0; j < 4; j++)
                acc[i][j] = __builtin_amdgcn_mfma_f32_16x16x32_bf16(af[i], bf[j], acc[i][j], 0, 0, 0);

        __syncthreads();   // all waves done reading LDS before next overwrite
    }

    // epilogue: C/D layout col = lane&15, row = quad*4 + reg  [m89/m91 verified]
#pragma unroll
    for (int j = 0; j < 4; j++) {
        const int col = n0 + wx * 64 + j * 16 + lrow;
        const float bj = bias[col];
#pragma unroll
        for (int i = 0; i < 4; i++) {
            const int row = m0 + wy * 64 + i * 16 + quad * 4;
            float* cp = C + (size_t)row * GEMM_N + col;
#pragma unroll
            for (int r = 0; r < 4; r++)
                cp[(size_t)r * GEMM_N] = acc[i][j][r] + bj;
        }
    }
}

// ---------------- launch ----------------

extern "C" void kernel_launch(void* const* d_in, const int* in_sizes, int n_in,
                              void* d_out, int out_size, void* d_ws, size_t ws_size,
                              hipStream_t stream) {
    const float* x      = (const float*)d_in[0];   // [4,2048,4096] = [8192,4096]
    const float* weight = (const float*)d_in[1];   // [4096,4096]
    const float* bias   = (const float*)d_in[2];   // [4096]
    const float* sw     = (const float*)d_in[3];   // [nnz]
    const int*   sidx   = (const int*)d_in[4];     // [2,nnz]
    const int nnz = in_sizes[3];

    const size_t welems = (size_t)GEMM_N * GEMM_K;        // 16,777,216
    const size_t xelems = (size_t)GEMM_M * GEMM_K;        // 33,554,432

    // scratch layout: fp32 W_new lives in d_out (consumed before GEMM writes it);
    // bf16 W_new (32 MiB) + bf16 X (64 MiB) in d_ws.
    float*    wtmp = (float*)d_out;
    uint16_t* Wb   = (uint16_t*)d_ws;
    uint16_t* Xb   = (uint16_t*)((char*)d_ws + welems * sizeof(uint16_t));

    // 1. W_new = W
    copy_w_kernel<<<dim3((int)(welems / 4 / 256)), 256, 0, stream>>>(
        (const float4*)weight, (float4*)wtmp, (int)(welems / 4));
    // 2. W_new += scatter(delta)
    scatter_add_kernel<<<dim3((nnz + 255) / 256), 256, 0, stream>>>(
        wtmp, sw, sidx, sidx + nnz, nnz);
    // 3. bf16 casts
    cvt_bf16_kernel<<<dim3((int)(welems / 8 / 256)), 256, 0, stream>>>(wtmp, Wb, welems / 8);
    cvt_bf16_kernel<<<dim3((int)(xelems / 8 / 256)), 256, 0, stream>>>(x,    Xb, xelems / 8);
    // 4. GEMM + bias
    gemm_bt_kernel<<<dim3(GEMM_N / BN, GEMM_M / BM), 256, 0, stream>>>(
        Xb, Wb, bias, (float*)d_out);
}

// Round 2
// 596.617 us; speedup vs baseline: 1.0166x; 1.0166x over previous
//
#include <hip/hip_runtime.h>
#include <hip/hip_bf16.h>
#include <stdint.h>

typedef float v4f __attribute__((ext_vector_type(4)));
typedef short v8s __attribute__((ext_vector_type(8)));

#define GEMM_M 8192
#define GEMM_N 4096
#define GEMM_K 4096
#define BM 128
#define BN 128
#define BK 32

// ---------------- prep ----------------

__device__ __forceinline__ uint16_t f2bf(float f) {
    union { float f; uint32_t u; } v; v.f = f;
    uint32_t r = v.u + 0x7FFFu + ((v.u >> 16) & 1u);   // round-to-nearest-even
    return (uint16_t)(r >> 16);
}

__device__ __forceinline__ float bf2f(uint16_t h) {
    union { uint32_t u; float f; } v; v.u = ((uint32_t)h) << 16;
    return v.f;
}

__device__ __forceinline__ void cvt8(const float* __restrict__ s, uint16_t* __restrict__ d) {
    float4 a = ((const float4*)s)[0];
    float4 b = ((const float4*)s)[1];
    union { v8s v; uint16_t u[8]; } o;
    o.u[0] = f2bf(a.x); o.u[1] = f2bf(a.y); o.u[2] = f2bf(a.z); o.u[3] = f2bf(a.w);
    o.u[4] = f2bf(b.x); o.u[5] = f2bf(b.y); o.u[6] = f2bf(b.z); o.u[7] = f2bf(b.w);
    *(v8s*)d = o.v;
}

// One kernel converts both X (33.5M elems) and W (16.7M elems) to bf16.
// 8 elems/thread; blocks [0, x8blk) handle X, the rest handle W.
__global__ void prep_cvt_kernel(const float* __restrict__ X, const float* __restrict__ W,
                                uint16_t* __restrict__ Xb, uint16_t* __restrict__ Wb,
                                size_t x8) {
    size_t i = (size_t)blockIdx.x * blockDim.x + threadIdx.x;
    if (i < x8) {
        cvt8(X + i * 8, Xb + i * 8);
    } else {
        size_t j = i - x8;                 // < welems/8 by grid construction
        cvt8(W + j * 8, Wb + j * 8);
    }
}

// Scatter-add deltas into the bf16 weight via 32-bit CAS on the containing word.
// Duplicates (expected ~2k collisions out of 262144) are handled by the CAS retry.
__global__ void scatter_bf16_kernel(uint16_t* __restrict__ Wb, const float* __restrict__ vals,
                                    const int* __restrict__ rows, const int* __restrict__ cols,
                                    int nnz) {
    int i = blockIdx.x * blockDim.x + threadIdx.x;
    if (i >= nnz) return;
    size_t idx = (size_t)rows[i] * GEMM_K + cols[i];
    uint32_t* addr = (uint32_t*)Wb + (idx >> 1);
    const bool hi = idx & 1;
    const float v = vals[i];   // * SCALING=1.0
    uint32_t cur = *addr, assumed;
    do {
        assumed = cur;
        uint16_t h = hi ? (uint16_t)(assumed >> 16) : (uint16_t)(assumed & 0xFFFFu);
        uint16_t nh = f2bf(bf2f(h) + v);
        uint32_t nw = hi ? ((assumed & 0x0000FFFFu) | ((uint32_t)nh << 16))
                         : ((assumed & 0xFFFF0000u) | (uint32_t)nh);
        if (nw == assumed) break;
        cur = atomicCAS(addr, assumed, nw);
    } while (cur != assumed);
}

// ---------------- GEMM (m97 structure, unchanged from round 1) ----------------
// C[M,N] = A[M,K] (bf16, row-major) * B[N,K]^T (bf16, row-major) + bias[N]
// 256 threads = 4 waves; each wave computes a 64x64 sub-tile as 4x4 MFMAs of 16x16x32.

__device__ __forceinline__ void gload_lds16(const void* g, void* lds) {
    __builtin_amdgcn_global_load_lds(
        (const __attribute__((address_space(1))) void*)(uintptr_t)g,
        (__attribute__((address_space(3))) void*)(uintptr_t)lds,
        16, 0, 0);
}

__global__ __launch_bounds__(256) void gemm_bt_kernel(
    const uint16_t* __restrict__ A,   // [M,K] bf16 bits
    const uint16_t* __restrict__ B,   // [N,K] bf16 bits
    const float* __restrict__ bias,   // [N]
    float* __restrict__ C)            // [M,N] fp32
{
    __shared__ __attribute__((aligned(16))) uint16_t As[BM * BK];  // 8 KiB, unpadded (global_load_lds)
    __shared__ __attribute__((aligned(16))) uint16_t Bs[BN * BK];  // 8 KiB

    const int tid  = threadIdx.x;
    const int lane = tid & 63;
    const int wv   = tid >> 6;     // wave id 0..3
    const int wy   = wv >> 1;      // m half (0,1)
    const int wx   = wv & 1;       // n half (0,1)
    const int lrow = lane & 15;
    const int quad = lane >> 4;

    const int m0 = blockIdx.y * BM;
    const int n0 = blockIdx.x * BN;

    // staging: 512 x 16B transfers per tile; transfer idx = wv*2+j (wave-uniform),
    // elem8 = idx*64 + lane; LDS dst = base + elem8*16 (lane-contiguous, HW requirement)
    const int e0 = (wv * 2 + 0) * 64 + lane;
    const int e1 = (wv * 2 + 1) * 64 + lane;
    const uint16_t* a_g0 = A + (size_t)(m0 + (e0 >> 2)) * GEMM_K + (e0 & 3) * 8;
    const uint16_t* a_g1 = A + (size_t)(m0 + (e1 >> 2)) * GEMM_K + (e1 & 3) * 8;
    const uint16_t* b_g0 = B + (size_t)(n0 + (e0 >> 2)) * GEMM_K + (e0 & 3) * 8;
    const uint16_t* b_g1 = B + (size_t)(n0 + (e1 >> 2)) * GEMM_K + (e1 & 3) * 8;
    uint16_t* a_l0 = As + e0 * 8;
    uint16_t* a_l1 = As + e1 * 8;
    uint16_t* b_l0 = Bs + e0 * 8;
    uint16_t* b_l1 = Bs + e1 * 8;

    v4f acc[4][4];
#pragma unroll
    for (int i = 0; i < 4; i++)
#pragma unroll
        for (int j = 0; j < 4; j++) acc[i][j] = (v4f){0.f, 0.f, 0.f, 0.f};

    for (int k0 = 0; k0 < GEMM_K; k0 += BK) {
        gload_lds16(a_g0 + k0, a_l0);
        gload_lds16(a_g1 + k0, a_l1);
        gload_lds16(b_g0 + k0, b_l0);
        gload_lds16(b_g1 + k0, b_l1);
        __syncthreads();   // compiler emits vmcnt(0) drain before s_barrier -> tiles ready

        v8s af[4], bf[4];
#pragma unroll
        for (int t = 0; t < 4; t++)
            af[t] = *(const v8s*)(As + (wy * 64 + t * 16 + lrow) * BK + quad * 8);
#pragma unroll
        for (int t = 0; t < 4; t++)
            bf[t] = *(const v8s*)(Bs + (wx * 64 + t * 16 + lrow) * BK + quad * 8);

#pragma unroll
        for (int i = 0; i < 4; i++)
#pragma unroll
            for (int j = 0; j < 4; j++)
                acc[i][j] = __builtin_amdgcn_mfma_f32_16x16x32_bf16(af[i], bf[j], acc[i][j], 0, 0, 0);

        __syncthreads();   // all waves done reading LDS before next overwrite
    }

    // epilogue: C/D layout col = lane&15, row = quad*4 + reg  [m89/m91 verified]
#pragma unroll
    for (int j = 0; j < 4; j++) {
        const int col = n0 + wx * 64 + j * 16 + lrow;
        const float bj = bias[col];
#pragma unroll
        for (int i = 0; i < 4; i++) {
            const int row = m0 + wy * 64 + i * 16 + quad * 4;
            float* cp = C + (size_t)row * GEMM_N + col;
#pragma unroll
            for (int r = 0; r < 4; r++)
                cp[(size_t)r * GEMM_N] = acc[i][j][r] + bj;
        }
    }
}

// ---------------- launch ----------------

extern "C" void kernel_launch(void* const* d_in, const int* in_sizes, int n_in,
                              void* d_out, int out_size, void* d_ws, size_t ws_size,
                              hipStream_t stream) {
    const float* x      = (const float*)d_in[0];   // [4,2048,4096] = [8192,4096]
    const float* weight = (const float*)d_in[1];   // [4096,4096]
    const float* bias   = (const float*)d_in[2];   // [4096]
    const float* sw     = (const float*)d_in[3];   // [nnz]
    const int*   sidx   = (const int*)d_in[4];     // [2,nnz]
    const int nnz = in_sizes[3];

    const size_t welems = (size_t)GEMM_N * GEMM_K;        // 16,777,216
    const size_t xelems = (size_t)GEMM_M * GEMM_K;        // 33,554,432

    // scratch layout: bf16 W_new (32 MiB) + bf16 X (64 MiB) in d_ws.
    uint16_t* Wb = (uint16_t*)d_ws;
    uint16_t* Xb = (uint16_t*)((char*)d_ws + welems * sizeof(uint16_t));

    const size_t x8 = xelems / 8;                          // 4,194,304 threads for X
    const size_t w8 = welems / 8;                          // 2,097,152 threads for W
    const int prep_blocks = (int)((x8 + w8) / 256);        // 24,576 (exact)

    // 1. fused bf16 conversion of X and W (single BW-bound kernel)
    prep_cvt_kernel<<<dim3(prep_blocks), 256, 0, stream>>>(x, weight, Xb, Wb, x8);
    // 2. scatter deltas into bf16 W via 32-bit CAS
    scatter_bf16_kernel<<<dim3((nnz + 255) / 256), 256, 0, stream>>>(
        Wb, sw, sidx, sidx + nnz, nnz);
    // 3. GEMM + bias
    gemm_bt_kernel<<<dim3(GEMM_N / BN, GEMM_M / BM), 256, 0, stream>>>(
        Xb, Wb, bias, (float*)d_out);
}

// Round 3
// 593.876 us; speedup vs baseline: 1.0213x; 1.0046x over previous
//
#include <hip/hip_runtime.h>
#include <hip/hip_bf16.h>
#include <stdint.h>

typedef float v4f __attribute__((ext_vector_type(4)));
typedef short v8s __attribute__((ext_vector_type(8)));

#define GEMM_M 8192
#define GEMM_N 4096
#define GEMM_K 4096
#define BM 128
#define BN 128
#define BK 64

// ---------------- prep ----------------

__device__ __forceinline__ uint16_t f2bf(float f) {
    union { float f; uint32_t u; } v; v.f = f;
    uint32_t r = v.u + 0x7FFFu + ((v.u >> 16) & 1u);   // round-to-nearest-even
    return (uint16_t)(r >> 16);
}

__device__ __forceinline__ float bf2f(uint16_t h) {
    union { uint32_t u; float f; } v; v.u = ((uint32_t)h) << 16;
    return v.f;
}

__device__ __forceinline__ void cvt8(const float* __restrict__ s, uint16_t* __restrict__ d) {
    float4 a = ((const float4*)s)[0];
    float4 b = ((const float4*)s)[1];
    union { v8s v; uint16_t u[8]; } o;
    o.u[0] = f2bf(a.x); o.u[1] = f2bf(a.y); o.u[2] = f2bf(a.z); o.u[3] = f2bf(a.w);
    o.u[4] = f2bf(b.x); o.u[5] = f2bf(b.y); o.u[6] = f2bf(b.z); o.u[7] = f2bf(b.w);
    *(v8s*)d = o.v;
}

// One kernel converts both X (33.5M elems) and W (16.7M elems) to bf16.
__global__ void prep_cvt_kernel(const float* __restrict__ X, const float* __restrict__ W,
                                uint16_t* __restrict__ Xb, uint16_t* __restrict__ Wb,
                                size_t x8) {
    size_t i = (size_t)blockIdx.x * blockDim.x + threadIdx.x;
    if (i < x8) {
        cvt8(X + i * 8, Xb + i * 8);
    } else {
        size_t j = i - x8;
        cvt8(W + j * 8, Wb + j * 8);
    }
}

// Scatter-add deltas into the bf16 weight via 32-bit CAS on the containing word.
__global__ void scatter_bf16_kernel(uint16_t* __restrict__ Wb, const float* __restrict__ vals,
                                    const int* __restrict__ rows, const int* __restrict__ cols,
                                    int nnz) {
    int i = blockIdx.x * blockDim.x + threadIdx.x;
    if (i >= nnz) return;
    size_t idx = (size_t)rows[i] * GEMM_K + cols[i];
    uint32_t* addr = (uint32_t*)Wb + (idx >> 1);
    const bool hi = idx & 1;
    const float v = vals[i];   // * SCALING=1.0
    uint32_t cur = *addr, assumed;
    do {
        assumed = cur;
        uint16_t h = hi ? (uint16_t)(assumed >> 16) : (uint16_t)(assumed & 0xFFFFu);
        uint16_t nh = f2bf(bf2f(h) + v);
        uint32_t nw = hi ? ((assumed & 0x0000FFFFu) | ((uint32_t)nh << 16))
                         : ((assumed & 0xFFFF0000u) | (uint32_t)nh);
        if (nw == assumed) break;
        cur = atomicCAS(addr, assumed, nw);
    } while (cur != assumed);
}

// ---------------- GEMM ----------------
// C[M,N] = A[M,K] bf16 * B[N,K]^T bf16 + bias[N], fp32 out.
// BK=64 (half the barrier drains of BK=32), XOR-swizzled LDS k-chunks to kill
// bank conflicts: lane l of a staging transfer fetches global k-chunk
// kc = (l&7)^(l>>3) for LDS row (l>>3); read side applies chunk^(row&7).
// global_load_lds dst stays wave-uniform-base + lane*16 (HW requirement);
// only the per-lane GLOBAL source address is permuted.

__device__ __forceinline__ void gload_lds16(const void* g, void* lds) {
    __builtin_amdgcn_global_load_lds(
        (const __attribute__((address_space(1))) void*)(uintptr_t)g,
        (__attribute__((address_space(3))) void*)(uintptr_t)lds,
        16, 0, 0);
}

__global__ __launch_bounds__(256) void gemm_bt_kernel(
    const uint16_t* __restrict__ A,   // [M,K] bf16 bits
    const uint16_t* __restrict__ B,   // [N,K] bf16 bits
    const float* __restrict__ bias,   // [N]
    float* __restrict__ C)            // [M,N] fp32
{
    __shared__ __attribute__((aligned(16))) uint16_t As[BM * BK];  // 16 KiB
    __shared__ __attribute__((aligned(16))) uint16_t Bs[BN * BK];  // 16 KiB

    const int tid  = threadIdx.x;
    const int lane = tid & 63;
    const int wv   = tid >> 6;     // wave id 0..3
    const int wy   = wv >> 1;      // m half (0,1)
    const int wx   = wv & 1;       // n half (0,1)
    const int lrow = lane & 15;
    const int quad = lane >> 4;

    const int m0 = blockIdx.y * BM;
    const int n0 = blockIdx.x * BN;

    // --- staging addressing ---
    // transfer (wv, i, lane): LDS elem8 e = (wv*4+i)*64 + lane  (lane-contiguous)
    // LDS row  = e>>3 = wv*32 + i*8 + (lane>>3)
    // global k-chunk fetched = (lane&7) ^ (lane>>3)   [XOR swizzle]
    const int srow = wv * 32 + (lane >> 3);                 // + i*8 per transfer
    const int skc  = ((lane & 7) ^ (lane >> 3)) * 8;        // element offset in k
    const uint16_t* a_g = A + (size_t)(m0 + srow) * GEMM_K + skc;
    const uint16_t* b_g = B + (size_t)(n0 + srow) * GEMM_K + skc;
    uint16_t* a_l = As + (size_t)(wv * 256 + lane) * 8;     // + i*512 elems per transfer
    uint16_t* b_l = Bs + (size_t)(wv * 256 + lane) * 8;

    v4f acc[4][4];
#pragma unroll
    for (int i = 0; i < 4; i++)
#pragma unroll
        for (int j = 0; j < 4; j++) acc[i][j] = (v4f){0.f, 0.f, 0.f, 0.f};

    // fragment read: row r holds chunk c at LDS elem r*64 + (c ^ (r&7))*8
    const int xr = lrow & 7;   // row&7 for all fragment rows this lane touches

    for (int k0 = 0; k0 < GEMM_K; k0 += BK) {
#pragma unroll
        for (int i = 0; i < 4; i++) {
            gload_lds16(a_g + k0 + (size_t)i * 8 * GEMM_K, a_l + i * 512);
            gload_lds16(b_g + k0 + (size_t)i * 8 * GEMM_K, b_l + i * 512);
        }
        __syncthreads();

#pragma unroll
        for (int h = 0; h < 2; h++) {
            v8s af[4], bf[4];
#pragma unroll
            for (int t = 0; t < 4; t++) {
                const int row = wy * 64 + t * 16 + lrow;
                af[t] = *(const v8s*)(As + row * BK + (((h * 4 + quad) ^ xr) * 8));
            }
#pragma unroll
            for (int t = 0; t < 4; t++) {
                const int row = wx * 64 + t * 16 + lrow;
                bf[t] = *(const v8s*)(Bs + row * BK + (((h * 4 + quad) ^ xr) * 8));
            }
#pragma unroll
            for (int i = 0; i < 4; i++)
#pragma unroll
                for (int j = 0; j < 4; j++)
                    acc[i][j] = __builtin_amdgcn_mfma_f32_16x16x32_bf16(af[i], bf[j], acc[i][j], 0, 0, 0);
        }

        __syncthreads();
    }

    // epilogue: C/D layout col = lane&15, row = quad*4 + reg  [m89/m91 verified]
#pragma unroll
    for (int j = 0; j < 4; j++) {
        const int col = n0 + wx * 64 + j * 16 + lrow;
        const float bj = bias[col];
#pragma unroll
        for (int i = 0; i < 4; i++) {
            const int row = m0 + wy * 64 + i * 16 + quad * 4;
            float* cp = C + (size_t)row * GEMM_N + col;
#pragma unroll
            for (int r = 0; r < 4; r++)
                cp[(size_t)r * GEMM_N] = acc[i][j][r] + bj;
        }
    }
}

// ---------------- launch ----------------

extern "C" void kernel_launch(void* const* d_in, const int* in_sizes, int n_in,
                              void* d_out, int out_size, void* d_ws, size_t ws_size,
                              hipStream_t stream) {
    const float* x      = (const float*)d_in[0];   // [4,2048,4096] = [8192,4096]
    const float* weight = (const float*)d_in[1];   // [4096,4096]
    const float* bias   = (const float*)d_in[2];   // [4096]
    const float* sw     = (const float*)d_in[3];   // [nnz]
    const int*   sidx   = (const int*)d_in[4];     // [2,nnz]
    const int nnz = in_sizes[3];

    const size_t welems = (size_t)GEMM_N * GEMM_K;        // 16,777,216
    const size_t xelems = (size_t)GEMM_M * GEMM_K;        // 33,554,432

    uint16_t* Wb = (uint16_t*)d_ws;
    uint16_t* Xb = (uint16_t*)((char*)d_ws + welems * sizeof(uint16_t));

    const size_t x8 = xelems / 8;
    const size_t w8 = welems / 8;
    const int prep_blocks = (int)((x8 + w8) / 256);

    prep_cvt_kernel<<<dim3(prep_blocks), 256, 0, stream>>>(x, weight, Xb, Wb, x8);
    scatter_bf16_kernel<<<dim3((nnz + 255) / 256), 256, 0, stream>>>(
        Wb, sw, sidx, sidx + nnz, nnz);
    gemm_bt_kernel<<<dim3(GEMM_N / BN, GEMM_M / BM), 256, 0, stream>>>(
        Xb, Wb, bias, (float*)d_out);
}